// Round 5
// baseline (93.368 us; speedup 1.0000x reference)
//
#include <hip/hip_runtime.h>
#include <hip/hip_bf16.h>
#include <math.h>

#define C1F  0.577078016f   // 0.4 * log2(e)
#define C2F  0.865617024f   // 0.6 * log2(e)

// ws byte offsets
#define WS_CNT 0                          // 16 x i64
#define WS_AGG 128                        // 1024 x i64  (ends 8320)
#define WS_G   8320                       // 2048*64 f32
#define WS_DCL (8320 + 524288)            // 2048*4 f32  (ends 573056)

typedef float __attribute__((ext_vector_type(2))) f32x2;
typedef float __attribute__((ext_vector_type(4))) f32x4;

__device__ __forceinline__ f32x2 pk_add(f32x2 a, f32x2 b) {
    f32x2 d; asm("v_pk_add_f32 %0, %1, %2" : "=v"(d) : "v"(a), "v"(b)); return d;
}
__device__ __forceinline__ void pk_fma_acc(f32x2& c, f32x2 a, f32x2 b) {
    asm("v_pk_fma_f32 %0, %1, %2, %0" : "+v"(c) : "v"(a), "v"(b));
}

// wave64 sum via DPP (no DS pipe). Full sum valid in lane 63.
__device__ __forceinline__ float dpp_sum(float x) {
    float y;
    y = __int_as_float(__builtin_amdgcn_update_dpp(0, __float_as_int(x), 0x111, 0xf, 0xf, true)); x += y;
    y = __int_as_float(__builtin_amdgcn_update_dpp(0, __float_as_int(x), 0x112, 0xf, 0xf, true)); x += y;
    y = __int_as_float(__builtin_amdgcn_update_dpp(0, __float_as_int(x), 0x114, 0xf, 0xf, true)); x += y;
    y = __int_as_float(__builtin_amdgcn_update_dpp(0, __float_as_int(x), 0x118, 0xf, 0xf, true)); x += y;
    y = __int_as_float(__builtin_amdgcn_update_dpp(0, __float_as_int(x), 0x142, 0xa, 0xf, true)); x += y;
    y = __int_as_float(__builtin_amdgcn_update_dpp(0, __float_as_int(x), 0x143, 0xc, 0xf, true)); x += y;
    return x;
}

// ---------------------------------------------------------------------------
// k_proj: ohm fill + g = pin @ Wl^T + dcl[i,h] = C2*dot(w, g_ih) + label cnt
// grid 512 x 256 : block = 4 rows, thread = (row, out-col o)
// ---------------------------------------------------------------------------
__global__ __launch_bounds__(256) void k_proj(
    const float* __restrict__ x, const float* __restrict__ ohm,
    const float* __restrict__ Wl, const float* __restrict__ Wattn,
    unsigned char* __restrict__ ws)
{
    float* g   = (float*)(ws + WS_G);
    float* dcl = (float*)(ws + WS_DCL);
    unsigned long long* cnt = (unsigned long long*)(ws + WS_CNT);

    int t = threadIdx.x;
    int r = blockIdx.x * 4 + (t >> 6);
    int o = t & 63;

    f32x4 oh[4]; float rs = 0.f;
    const f32x4* ohp = (const f32x4*)&ohm[r*16];
    #pragma unroll
    for (int q = 0; q < 4; ++q) { oh[q] = ohp[q]; rs += oh[q][0]+oh[q][1]+oh[q][2]+oh[q][3]; }
    if (rs == 0.f) {
        f32x4 c = {0.0625f, 0.0625f, 0.0625f, 0.0625f};
        #pragma unroll
        for (int q = 0; q < 4; ++q) oh[q] = c;
    }

    float acc = 0.f;
    const f32x4* xp = (const f32x4*)&x[r*64];
    const f32x4* wp = (const f32x4*)&Wl[o*80];
    #pragma unroll
    for (int q = 0; q < 16; ++q) {
        f32x4 a = xp[q], b = wp[q];
        acc = fmaf(a[0],b[0],acc); acc = fmaf(a[1],b[1],acc);
        acc = fmaf(a[2],b[2],acc); acc = fmaf(a[3],b[3],acc);
    }
    #pragma unroll
    for (int q = 0; q < 4; ++q) {
        f32x4 b = wp[16+q];
        acc = fmaf(oh[q][0],b[0],acc); acc = fmaf(oh[q][1],b[1],acc);
        acc = fmaf(oh[q][2],b[2],acc); acc = fmaf(oh[q][3],b[3],acc);
    }
    g[r*64 + o] = acc;

    float dot = Wattn[o & 15] * acc;
    #pragma unroll
    for (int m2 = 1; m2 < 16; m2 <<= 1) dot += __shfl_xor(dot, m2);
    if ((o & 15) == 0) dcl[r*4 + (o >> 4)] = C2F * dot;

    if (t < 16) {  // exact label counts, fixed-point 2^20 (ohm in {0,1,1/16})
        float c = 0.f;
        for (int rr = 0; rr < 4; ++rr) {
            int r2 = blockIdx.x*4 + rr; float s = 0.f;
            #pragma unroll
            for (int k = 0; k < 16; ++k) s += ohm[r2*16+k];
            c += (s == 0.f) ? 0.0625f : ohm[r2*16+t];
        }
        atomicAdd(&cnt[t], (unsigned long long)__float2ll_rn(c * 1048576.0f));
    }
}

// ---------------------------------------------------------------------------
// k_attn: flash attention, no shift (constant per-row factor cancels in a/l).
// grid 512 x 512. Double-buffered global_load_lds staging with XOR swizzle,
// counted vmcnt, raw barriers, packed-f32 + fma-abs inner loop, DPP epilogue.
// ---------------------------------------------------------------------------
__global__ __launch_bounds__(512, 4) void k_attn(
    const float* __restrict__ ohm, const float* __restrict__ Wattn,
    unsigned char* __restrict__ ws, float* __restrict__ hout)
{
    float* g   = (float*)(ws + WS_G);
    float* dcl = (float*)(ws + WS_DCL);
    unsigned long long* agg = (unsigned long long*)(ws + WS_AGG);

    __shared__ float gl[2][8192];   // 64 KiB double buffer, swizzled layout
    __shared__ float shh[256];
    __shared__ float ohmf[64];

    int t = threadIdx.x, bid = blockIdx.x;
    int wid = t >> 6, l = t & 63;
    int ipair = wid >> 2, h = wid & 3;
    int iA = bid*4 + ipair*2, iB = iA + 1;

    // read-side swizzle: LDS word = r*64 + (col ^ ((r&7)<<2)); r&7 == l&7 here
    int sxor = (l & 7) << 2;
    int col0 = (h*16 +  0) ^ sxor;
    int col1 = (h*16 +  4) ^ sxor;
    int col2 = (h*16 +  8) ^ sxor;
    int col3 = (h*16 + 12) ^ sxor;

    // stage-side: lane l serves (row-in-chunk = l>>4, 16B slot l&15); source is
    // inverse-swizzled so linear LDS writes produce the swizzled layout.
    int rowin = l >> 4;
    int sbase = rowin*64 + ((4*(l & 15)) ^ (rowin << 2));

    f32x2 w2[8], gA2[8], gB2[8];
    #pragma unroll
    for (int q = 0; q < 8; ++q) {
        w2[q]  = *(const f32x2*)&Wattn[2*q];
        gA2[q] = *(const f32x2*)&g[iA*64 + h*16 + 2*q];
        gB2[q] = *(const f32x2*)&g[iB*64 + h*16 + 2*q];
    }
    f32x2 accA2[8], accB2[8];
    f32x2 z2 = {0.f, 0.f};
    #pragma unroll
    for (int q = 0; q < 8; ++q) { accA2[q] = z2; accB2[q] = z2; }
    float lA = 0.f, lB = 0.f;

    const float* dp = dcl + (l*4 + h);

    // prologue: stage tile 0 into gl[0]
    #pragma unroll
    for (int c = 0; c < 4; ++c) {
        int chunk = 4*wid + c;
        int so = chunk*256 + (sbase ^ ((c & 1) << 4));
        __builtin_amdgcn_global_load_lds(
            (const __attribute__((address_space(1))) void*)(g + so),
            (__attribute__((address_space(3))) void*)&gl[0][chunk*256], 16, 0, 0);
    }

    int buf = 0;
    for (int tile = 0; tile < 16; ++tile) {
        // dj loads FIRST (older than prefetch -> compiler waits vmcnt(4), not 0)
        float dj0 = dp[tile*512];
        float dj1 = dp[tile*512 + 256];
        __builtin_amdgcn_sched_barrier(0);
        if (tile < 15) {
            const float* gt = g + (tile+1)*8192;
            float* dst = &gl[buf ^ 1][0];
            #pragma unroll
            for (int c = 0; c < 4; ++c) {
                int chunk = 4*wid + c;
                int so = chunk*256 + (sbase ^ ((c & 1) << 4));
                __builtin_amdgcn_global_load_lds(
                    (const __attribute__((address_space(1))) void*)(gt + so),
                    (__attribute__((address_space(3))) void*)(dst + chunk*256), 16, 0, 0);
            }
            asm volatile("s_waitcnt vmcnt(4)" ::: "memory");  // tile-t data + djs done
        } else {
            asm volatile("s_waitcnt vmcnt(0)" ::: "memory");
        }
        asm volatile("s_barrier" ::: "memory");

        const float* bp = &gl[buf][0];
        #pragma unroll
        for (int kk = 0; kk < 2; ++kk) {
            float djk = kk ? dj1 : dj0;
            int rb = (kk*64 + l) << 6;
            f32x4 q0 = *(const f32x4*)(bp + rb + col0);
            f32x4 q1 = *(const f32x4*)(bp + rb + col1);
            f32x4 q2 = *(const f32x4*)(bp + rb + col2);
            f32x4 q3 = *(const f32x4*)(bp + rb + col3);
            f32x2 gv[8] = {
                __builtin_shufflevector(q0,q0,0,1), __builtin_shufflevector(q0,q0,2,3),
                __builtin_shufflevector(q1,q1,0,1), __builtin_shufflevector(q1,q1,2,3),
                __builtin_shufflevector(q2,q2,0,1), __builtin_shufflevector(q2,q2,2,3),
                __builtin_shufflevector(q3,q3,0,1), __builtin_shufflevector(q3,q3,2,3) };
            float sA0 = 0.f, sA1 = 0.f, sB0 = 0.f, sB1 = 0.f;
            #pragma unroll
            for (int q = 0; q < 8; ++q) {
                f32x2 ta = pk_add(gA2[q], gv[q]);
                f32x2 tb = pk_add(gB2[q], gv[q]);
                sA0 = fmaf(w2[q][0], fabsf(ta[0]), sA0);   // |.| = free VOP3 modifier
                sA1 = fmaf(w2[q][1], fabsf(ta[1]), sA1);
                sB0 = fmaf(w2[q][0], fabsf(tb[0]), sB0);
                sB1 = fmaf(w2[q][1], fabsf(tb[1]), sB1);
            }
            float pA = __builtin_amdgcn_exp2f(fmaf(C1F, sA0 + sA1, djk));
            float pB = __builtin_amdgcn_exp2f(fmaf(C1F, sB0 + sB1, djk));
            lA += pA; lB += pB;
            f32x2 ppA = {pA, pA}, ppB = {pB, pB};
            #pragma unroll
            for (int q = 0; q < 8; ++q) {
                pk_fma_acc(accA2[q], ppA, gv[q]);
                pk_fma_acc(accB2[q], ppB, gv[q]);
            }
        }
        asm volatile("s_barrier" ::: "memory");  // all waves done reading buf
        buf ^= 1;
    }

    // wave reduction via DPP -> lane 63
    float lAs = dpp_sum(lA), lBs = dpp_sum(lB);
    float hA[16], hB[16];
    #pragma unroll
    for (int q = 0; q < 8; ++q) {
        hA[2*q]   = dpp_sum(accA2[q][0]);
        hA[2*q+1] = dpp_sum(accA2[q][1]);
        hB[2*q]   = dpp_sum(accB2[q][0]);
        hB[2*q+1] = dpp_sum(accB2[q][1]);
    }
    if (l == 63) {
        float rA = 1.0f / lAs, rB = 1.0f / lBs;
        #pragma unroll
        for (int f = 0; f < 16; ++f) {
            float a = hA[f]*rA; a = fmaxf(a, 0.2f*a);
            float b = hB[f]*rB; b = fmaxf(b, 0.2f*b);
            hout[iA*64 + h*16 + f] = a;
            hout[iB*64 + h*16 + f] = b;
            shh[(ipair*2    )*64 + h*16 + f] = a;
            shh[(ipair*2 + 1)*64 + h*16 + f] = b;
        }
    }
    if (t < 64) {   // filled ohm for the block's 4 rows
        int rr = t >> 4, ll = t & 15;
        float v = ohm[(bid*4 + rr)*16 + ll];
        float s = v;
        #pragma unroll
        for (int m2 = 1; m2 < 16; m2 <<= 1) s += __shfl_xor(s, m2);
        ohmf[rr*16 + ll] = (s == 0.f) ? 0.0625f : v;
    }
    __syncthreads();

    // deterministic centroid partial agg: int64 fixed-point 2^26 (order-free)
    for (int v = t; v < 1024; v += 512) {
        int ll = v >> 6, d = v & 63;
        float s = 0.f;
        #pragma unroll
        for (int rr = 0; rr < 4; ++rr) s = fmaf(ohmf[rr*16 + ll], shh[rr*64 + d], s);
        atomicAdd(&agg[v], (unsigned long long)__float2ll_rn(s * 67108864.0f));
    }
}

// ---------------------------------------------------------------------------
// k_scores: rebuild centroids per block from agg/cnt, then cdist.
// ---------------------------------------------------------------------------
__global__ __launch_bounds__(256) void k_scores(
    unsigned char* __restrict__ ws, const float* __restrict__ hout,
    float* __restrict__ scores, float* __restrict__ missing)
{
    __shared__ float cl[16*68];
    unsigned long long* cnt = (unsigned long long*)(ws + WS_CNT);
    unsigned long long* agg = (unsigned long long*)(ws + WS_AGG);
    int t = threadIdx.x;

    for (int v = t; v < 1024; v += 256) {
        int ll = v >> 6, d = v & 63;
        long long a = (long long)agg[v];
        long long c = (long long)cnt[ll];
        cl[ll*68 + d] = (c == 0) ? 0.f : ((float)a / (float)c) * 0.015625f;
    }
    if (blockIdx.x == 0 && t < 16) missing[t] = (cnt[t] == 0) ? 1.0f : 0.0f;
    __syncthreads();

    int i = blockIdx.x*16 + (t >> 4), ll = t & 15;
    float s = 0.f;
    #pragma unroll 16
    for (int d = 0; d < 64; ++d) {
        float diff = hout[i*64 + d] - cl[ll*68 + d];
        s = fmaf(diff, diff, s);
    }
    scores[i*16 + ll] = -sqrtf(s);
}

// ---------------------------------------------------------------------------
extern "C" void kernel_launch(void* const* d_in, const int* in_sizes, int n_in,
                              void* d_out, int out_size, void* d_ws, size_t ws_size,
                              hipStream_t stream)
{
    const float* x     = (const float*)d_in[0];
    const float* ohm   = (const float*)d_in[1];
    const float* Wl    = (const float*)d_in[2];
    const float* Wattn = (const float*)d_in[3];
    unsigned char* ws  = (unsigned char*)d_ws;

    float* out     = (float*)d_out;
    float* scores  = out;
    float* hout    = out + 2048*16;
    float* missing = out + 2048*16 + 2048*64;

    hipMemsetAsync(d_ws, 0, 8320, stream);           // cnt + agg
    k_proj  <<<512, 256, 0, stream>>>(x, ohm, Wl, Wattn, ws);
    k_attn  <<<512, 512, 0, stream>>>(ohm, Wattn, ws, hout);
    k_scores<<<128, 256, 0, stream>>>(ws, hout, scores, missing);
}

// Round 7
// 61.051 us; speedup vs baseline: 1.5294x; 1.5294x over previous
//
#include <hip/hip_runtime.h>
#include <hip/hip_bf16.h>
#include <math.h>

#define C1F  0.577078016f   // 0.4 * log2(e)
#define C2F  0.865617024f   // 0.6 * log2(e)

// ws byte offsets
#define WS_CNT 0                          // 16 x i64
#define WS_AGG 128                        // 1024 x i64  (ends 8320)
#define WS_G   8320                       // 2048*64 f32
#define WS_DCL (8320 + 524288)            // 2048*4 f32  (ends 573056)

typedef float __attribute__((ext_vector_type(4))) f32x4;

// wave64 sum via DPP (no DS pipe). Full sum valid in lane 63.
__device__ __forceinline__ float dpp_sum(float x) {
    float y;
    y = __int_as_float(__builtin_amdgcn_update_dpp(0, __float_as_int(x), 0x111, 0xf, 0xf, true)); x += y;
    y = __int_as_float(__builtin_amdgcn_update_dpp(0, __float_as_int(x), 0x112, 0xf, 0xf, true)); x += y;
    y = __int_as_float(__builtin_amdgcn_update_dpp(0, __float_as_int(x), 0x114, 0xf, 0xf, true)); x += y;
    y = __int_as_float(__builtin_amdgcn_update_dpp(0, __float_as_int(x), 0x118, 0xf, 0xf, true)); x += y;
    y = __int_as_float(__builtin_amdgcn_update_dpp(0, __float_as_int(x), 0x142, 0xa, 0xf, true)); x += y;
    y = __int_as_float(__builtin_amdgcn_update_dpp(0, __float_as_int(x), 0x143, 0xc, 0xf, true)); x += y;
    return x;
}

// ---------------------------------------------------------------------------
// k_proj: ohm fill + g = pin @ Wl^T + dcl[i,h] = C2*dot(w, g_ih) + label cnt
// ---------------------------------------------------------------------------
__global__ __launch_bounds__(256) void k_proj(
    const float* __restrict__ x, const float* __restrict__ ohm,
    const float* __restrict__ Wl, const float* __restrict__ Wattn,
    unsigned char* __restrict__ ws)
{
    float* g   = (float*)(ws + WS_G);
    float* dcl = (float*)(ws + WS_DCL);
    unsigned long long* cnt = (unsigned long long*)(ws + WS_CNT);

    int t = threadIdx.x;
    int r = blockIdx.x * 4 + (t >> 6);
    int o = t & 63;

    f32x4 oh[4]; float rs = 0.f;
    const f32x4* ohp = (const f32x4*)&ohm[r*16];
    #pragma unroll
    for (int q = 0; q < 4; ++q) { oh[q] = ohp[q]; rs += oh[q][0]+oh[q][1]+oh[q][2]+oh[q][3]; }
    if (rs == 0.f) {
        f32x4 c = {0.0625f, 0.0625f, 0.0625f, 0.0625f};
        #pragma unroll
        for (int q = 0; q < 4; ++q) oh[q] = c;
    }

    float acc = 0.f;
    const f32x4* xp = (const f32x4*)&x[r*64];
    const f32x4* wp = (const f32x4*)&Wl[o*80];
    #pragma unroll
    for (int q = 0; q < 16; ++q) {
        f32x4 a = xp[q], b = wp[q];
        acc = fmaf(a[0],b[0],acc); acc = fmaf(a[1],b[1],acc);
        acc = fmaf(a[2],b[2],acc); acc = fmaf(a[3],b[3],acc);
    }
    #pragma unroll
    for (int q = 0; q < 4; ++q) {
        f32x4 b = wp[16+q];
        acc = fmaf(oh[q][0],b[0],acc); acc = fmaf(oh[q][1],b[1],acc);
        acc = fmaf(oh[q][2],b[2],acc); acc = fmaf(oh[q][3],b[3],acc);
    }
    g[r*64 + o] = acc;

    float dot = Wattn[o & 15] * acc;
    #pragma unroll
    for (int m2 = 1; m2 < 16; m2 <<= 1) dot += __shfl_xor(dot, m2);
    if ((o & 15) == 0) dcl[r*4 + (o >> 4)] = C2F * dot;

    if (t < 16) {  // exact label counts, fixed-point 2^20 (ohm in {0,1,1/16})
        float c = 0.f;
        for (int rr = 0; rr < 4; ++rr) {
            int r2 = blockIdx.x*4 + rr; float s = 0.f;
            #pragma unroll
            for (int k = 0; k < 16; ++k) s += ohm[r2*16+k];
            c += (s == 0.f) ? 0.0625f : ohm[r2*16+t];
        }
        atomicAdd(&cnt[t], (unsigned long long)__float2ll_rn(c * 1048576.0f));
    }
}

// ---------------------------------------------------------------------------
// k_attn: flash attention, no per-row shift (constant factor cancels in a/l).
// grid 512 x 512. Reg-staged double-buffered LDS (stride 68, 0-conflict),
// T14 split (loads 2 tiles ahead, ds_write 1 ahead), raw lgkm-only barrier
// (vmcnt never drained mid-loop), DPP epilogue.
// ---------------------------------------------------------------------------
__global__ __launch_bounds__(512, 4) void k_attn(
    const float* __restrict__ ohm, const float* __restrict__ Wattn,
    unsigned char* __restrict__ ws, float* __restrict__ hout)
{
    float* g   = (float*)(ws + WS_G);
    float* dcl = (float*)(ws + WS_DCL);
    unsigned long long* agg = (unsigned long long*)(ws + WS_AGG);

    __shared__ float gl[2][128*68];  // 69,632 B double buffer
    __shared__ float shh[256];
    __shared__ float ohmf[64];

    int t = threadIdx.x, bid = blockIdx.x;
    int wid = t >> 6, l = t & 63;
    int ipair = wid >> 2, h = wid & 3;
    int iA = bid*4 + ipair*2, iB = iA + 1;

    // staging geometry: thread t stages tile floats [t*16, t*16+16)
    const f32x4* gsrc = (const f32x4*)(g) + t*4;   // tile stride = 2048 f32x4
    float* wd0 = &gl[0][(t >> 2)*68 + (t & 3)*16];
    float* wd1 = &gl[1][(t >> 2)*68 + (t & 3)*16];

    float wv[16], gA[16], gB[16];
    #pragma unroll
    for (int f = 0; f < 16; ++f)
        wv[f] = __uint_as_float(__builtin_amdgcn_readfirstlane(__float_as_uint(Wattn[f])));
    #pragma unroll
    for (int f = 0; f < 16; ++f) {
        gA[f] = g[iA*64 + h*16 + f];
        gB[f] = g[iB*64 + h*16 + f];
    }
    float accA[16], accB[16];
    #pragma unroll
    for (int f = 0; f < 16; ++f) { accA[f] = 0.f; accB[f] = 0.f; }
    float lA = 0.f, lB = 0.f;

    const float* dp = dcl + (l*4 + h);

    // ---- prologue: load tile0+tile1 to regs, write tile0, prefetch dj ----
    f32x4 s0a = gsrc[0], s0b = gsrc[1], s0c = gsrc[2], s0d = gsrc[3];
    // tile 1 = +8192 floats = +2048 f32x4  (round-6 bug: was +512)
    f32x4 s1a = gsrc[2048+0], s1b = gsrc[2048+1], s1c = gsrc[2048+2], s1d = gsrc[2048+3];
    float djc0 = dp[0],   djc1 = dp[256];
    float djn0 = dp[512], djn1 = dp[768];
    *(f32x4*)(wd0+0) = s0a; *(f32x4*)(wd0+4)  = s0b;
    *(f32x4*)(wd0+8) = s0c; *(f32x4*)(wd0+12) = s0d;
    f32x4 sta = s1a, stb = s1b, stc = s1c, std_ = s1d;
    asm volatile("s_waitcnt lgkmcnt(0)\n\ts_barrier" ::: "memory");

    #pragma unroll
    for (int tile = 0; tile < 16; ++tile) {
        // stage: write tile+1 into other buffer; issue loads for tile+2
        if (tile < 15) {
            float* wd = (tile & 1) ? wd0 : wd1;
            *(f32x4*)(wd+0) = sta;  *(f32x4*)(wd+4)  = stb;
            *(f32x4*)(wd+8) = stc;  *(f32x4*)(wd+12) = std_;
        }
        float djn2_0 = 0.f, djn2_1 = 0.f;
        if (tile < 14) {
            const f32x4* src2 = gsrc + (tile+2)*2048;
            sta = src2[0]; stb = src2[1]; stc = src2[2]; std_ = src2[3];
            djn2_0 = dp[(tile+2)*512]; djn2_1 = dp[(tile+2)*512 + 256];
        }

        // compute tile from current buffer
        const float* bp = (tile & 1) ? &gl[1][0] : &gl[0][0];
        #pragma unroll
        for (int kk = 0; kk < 2; ++kk) {
            float djk = kk ? djc1 : djc0;
            const float* gj = bp + (kk*64 + l)*68 + h*16;
            f32x4 q0 = *(const f32x4*)(gj);
            f32x4 q1 = *(const f32x4*)(gj+4);
            f32x4 q2 = *(const f32x4*)(gj+8);
            f32x4 q3 = *(const f32x4*)(gj+12);
            float gv[16] = { q0[0],q0[1],q0[2],q0[3], q1[0],q1[1],q1[2],q1[3],
                             q2[0],q2[1],q2[2],q2[3], q3[0],q3[1],q3[2],q3[3] };
            float sA0=0.f, sA1=0.f, sB0=0.f, sB1=0.f;
            #pragma unroll
            for (int f = 0; f < 16; f += 2) {
                float ta0 = gA[f]   + gv[f];
                float ta1 = gA[f+1] + gv[f+1];
                float tb0 = gB[f]   + gv[f];
                float tb1 = gB[f+1] + gv[f+1];
                sA0 = fmaf(wv[f],   fabsf(ta0), sA0);   // |.| = free VOP3 modifier
                sA1 = fmaf(wv[f+1], fabsf(ta1), sA1);
                sB0 = fmaf(wv[f],   fabsf(tb0), sB0);
                sB1 = fmaf(wv[f+1], fabsf(tb1), sB1);
            }
            float pA = __builtin_amdgcn_exp2f(fmaf(C1F, sA0 + sA1, djk));
            float pB = __builtin_amdgcn_exp2f(fmaf(C1F, sB0 + sB1, djk));
            lA += pA; lB += pB;
            #pragma unroll
            for (int f = 0; f < 16; ++f) {
                accA[f] = fmaf(pA, gv[f], accA[f]);
                accB[f] = fmaf(pB, gv[f], accB[f]);
            }
        }
        // lgkm-only barrier: ds_writes visible, vmcnt prefetch stays in flight
        asm volatile("s_waitcnt lgkmcnt(0)\n\ts_barrier" ::: "memory");
        djc0 = djn0; djc1 = djn1;
        djn0 = djn2_0; djn1 = djn2_1;
    }

    // wave reduction via DPP -> lane 63
    float lAs = dpp_sum(lA), lBs = dpp_sum(lB);
    float hA[16], hB[16];
    #pragma unroll
    for (int f = 0; f < 16; ++f) { hA[f] = dpp_sum(accA[f]); hB[f] = dpp_sum(accB[f]); }

    if (l == 63) {
        float rA = 1.0f / lAs, rB = 1.0f / lBs;
        #pragma unroll
        for (int f = 0; f < 16; ++f) {
            float a = hA[f]*rA; a = fmaxf(a, 0.2f*a);
            float b = hB[f]*rB; b = fmaxf(b, 0.2f*b);
            hout[iA*64 + h*16 + f] = a;
            hout[iB*64 + h*16 + f] = b;
            shh[(ipair*2    )*64 + h*16 + f] = a;
            shh[(ipair*2 + 1)*64 + h*16 + f] = b;
        }
    }
    if (t < 64) {   // filled ohm for the block's 4 rows
        int rr = t >> 4, ll = t & 15;
        float v = ohm[(bid*4 + rr)*16 + ll];
        float s = v;
        #pragma unroll
        for (int m2 = 1; m2 < 16; m2 <<= 1) s += __shfl_xor(s, m2);
        ohmf[rr*16 + ll] = (s == 0.f) ? 0.0625f : v;
    }
    __syncthreads();

    // deterministic centroid partial agg: int64 fixed-point 2^26 (order-free)
    for (int v = t; v < 1024; v += 512) {
        int ll = v >> 6, d = v & 63;
        float s = 0.f;
        #pragma unroll
        for (int rr = 0; rr < 4; ++rr) s = fmaf(ohmf[rr*16 + ll], shh[rr*64 + d], s);
        atomicAdd(&agg[v], (unsigned long long)__float2ll_rn(s * 67108864.0f));
    }
}

// ---------------------------------------------------------------------------
// k_scores: rebuild centroids per block from agg/cnt, then cdist.
// ---------------------------------------------------------------------------
__global__ __launch_bounds__(256) void k_scores(
    unsigned char* __restrict__ ws, const float* __restrict__ hout,
    float* __restrict__ scores, float* __restrict__ missing)
{
    __shared__ float cl[16*68];
    unsigned long long* cnt = (unsigned long long*)(ws + WS_CNT);
    unsigned long long* agg = (unsigned long long*)(ws + WS_AGG);
    int t = threadIdx.x;

    for (int v = t; v < 1024; v += 256) {
        int ll = v >> 6, d = v & 63;
        long long a = (long long)agg[v];
        long long c = (long long)cnt[ll];
        cl[ll*68 + d] = (c == 0) ? 0.f : ((float)a / (float)c) * 0.015625f;
    }
    if (blockIdx.x == 0 && t < 16) missing[t] = (cnt[t] == 0) ? 1.0f : 0.0f;
    __syncthreads();

    int i = blockIdx.x*16 + (t >> 4), ll = t & 15;
    float s = 0.f;
    #pragma unroll 16
    for (int d = 0; d < 64; ++d) {
        float diff = hout[i*64 + d] - cl[ll*68 + d];
        s = fmaf(diff, diff, s);
    }
    scores[i*16 + ll] = -sqrtf(s);
}

// ---------------------------------------------------------------------------
extern "C" void kernel_launch(void* const* d_in, const int* in_sizes, int n_in,
                              void* d_out, int out_size, void* d_ws, size_t ws_size,
                              hipStream_t stream)
{
    const float* x     = (const float*)d_in[0];
    const float* ohm   = (const float*)d_in[1];
    const float* Wl    = (const float*)d_in[2];
    const float* Wattn = (const float*)d_in[3];
    unsigned char* ws  = (unsigned char*)d_ws;

    float* out     = (float*)d_out;
    float* scores  = out;
    float* hout    = out + 2048*16;
    float* missing = out + 2048*16 + 2048*64;

    hipMemsetAsync(d_ws, 0, 8320, stream);           // cnt + agg
    k_proj  <<<512, 256, 0, stream>>>(x, ohm, Wl, Wattn, ws);
    k_attn  <<<512, 512, 0, stream>>>(ohm, Wattn, ws, hout);
    k_scores<<<128, 256, 0, stream>>>(ws, hout, scores, missing);
}

// Round 8
// 57.745 us; speedup vs baseline: 1.6169x; 1.0572x over previous
//
#include <hip/hip_runtime.h>
#include <hip/hip_bf16.h>
#include <math.h>

#define C1F  0.577078016f   // 0.4 * log2(e)
#define C2F  0.865617024f   // 0.6 * log2(e)

// ws byte offsets
#define WS_CNT 0                          // 16 x i64
#define WS_AGG 128                        // 1024 x i64  (ends 8320)
#define WS_G   8320                       // 2048*64 f32
#define WS_DCL (8320 + 524288)            // dclT[4][2048] f32 (ends 573056)

typedef float __attribute__((ext_vector_type(4))) f32x4;

// 32-lane sum via DPP (no DS pipe). Sums valid in lanes 31 (lanes 0-31)
// and 63 (lanes 32-63). row_shr 1/2/4/8 then row_bcast15 into rows 1,3.
__device__ __forceinline__ float dpp_sum32(float x) {
    float y;
    y = __int_as_float(__builtin_amdgcn_update_dpp(0, __float_as_int(x), 0x111, 0xf, 0xf, true)); x += y;
    y = __int_as_float(__builtin_amdgcn_update_dpp(0, __float_as_int(x), 0x112, 0xf, 0xf, true)); x += y;
    y = __int_as_float(__builtin_amdgcn_update_dpp(0, __float_as_int(x), 0x114, 0xf, 0xf, true)); x += y;
    y = __int_as_float(__builtin_amdgcn_update_dpp(0, __float_as_int(x), 0x118, 0xf, 0xf, true)); x += y;
    y = __int_as_float(__builtin_amdgcn_update_dpp(0, __float_as_int(x), 0x142, 0xa, 0xf, true)); x += y;
    return x;
}

// ---------------------------------------------------------------------------
// k_proj: ohm fill + g = pin @ Wl^T + dclT[h][i] = C2*dot(w, g_ih) + label cnt
// ---------------------------------------------------------------------------
__global__ __launch_bounds__(256) void k_proj(
    const float* __restrict__ x, const float* __restrict__ ohm,
    const float* __restrict__ Wl, const float* __restrict__ Wattn,
    unsigned char* __restrict__ ws)
{
    float* g    = (float*)(ws + WS_G);
    float* dclT = (float*)(ws + WS_DCL);
    unsigned long long* cnt = (unsigned long long*)(ws + WS_CNT);

    int t = threadIdx.x;
    int r = blockIdx.x * 4 + (t >> 6);
    int o = t & 63;

    f32x4 oh[4]; float rs = 0.f;
    const f32x4* ohp = (const f32x4*)&ohm[r*16];
    #pragma unroll
    for (int q = 0; q < 4; ++q) { oh[q] = ohp[q]; rs += oh[q][0]+oh[q][1]+oh[q][2]+oh[q][3]; }
    if (rs == 0.f) {
        f32x4 c = {0.0625f, 0.0625f, 0.0625f, 0.0625f};
        #pragma unroll
        for (int q = 0; q < 4; ++q) oh[q] = c;
    }

    float acc = 0.f;
    const f32x4* xp = (const f32x4*)&x[r*64];
    const f32x4* wp = (const f32x4*)&Wl[o*80];
    #pragma unroll
    for (int q = 0; q < 16; ++q) {
        f32x4 a = xp[q], b = wp[q];
        acc = fmaf(a[0],b[0],acc); acc = fmaf(a[1],b[1],acc);
        acc = fmaf(a[2],b[2],acc); acc = fmaf(a[3],b[3],acc);
    }
    #pragma unroll
    for (int q = 0; q < 4; ++q) {
        f32x4 b = wp[16+q];
        acc = fmaf(oh[q][0],b[0],acc); acc = fmaf(oh[q][1],b[1],acc);
        acc = fmaf(oh[q][2],b[2],acc); acc = fmaf(oh[q][3],b[3],acc);
    }
    g[r*64 + o] = acc;

    float dot = Wattn[o & 15] * acc;
    #pragma unroll
    for (int m2 = 1; m2 < 16; m2 <<= 1) dot += __shfl_xor(dot, m2);
    if ((o & 15) == 0) dclT[(o >> 4)*2048 + r] = C2F * dot;   // transposed

    if (t < 16) {  // exact label counts, fixed-point 2^20 (ohm in {0,1,1/16})
        float c = 0.f;
        for (int rr = 0; rr < 4; ++rr) {
            int r2 = blockIdx.x*4 + rr; float s = 0.f;
            #pragma unroll
            for (int k = 0; k < 16; ++k) s += ohm[r2*16+k];
            c += (s == 0.f) ? 0.0625f : ohm[r2*16+t];
        }
        atomicAdd(&cnt[t], (unsigned long long)__float2ll_rn(c * 1048576.0f));
    }
}

// ---------------------------------------------------------------------------
// k_attn: flash attention. grid 512 x 512.
// pair = t>>5 -> (row r=p>>2, head h=p&3); sub = t&31; 1 row per thread.
// Round-3 LDS patterns (0-conflict measured): write (v>>4)*68+(v&15)*4,
// read (k*32+sub)*68+h*16 with h varying per half-wave.
// Round-7 pipeline: reg-staged dbuf, write t+1 / load t+2, lgkm-only barrier.
// ---------------------------------------------------------------------------
__global__ __launch_bounds__(512, 4) void k_attn(
    const float* __restrict__ ohm, const float* __restrict__ Wattn,
    unsigned char* __restrict__ ws, float* __restrict__ hout)
{
    float* g    = (float*)(ws + WS_G);
    float* dclT = (float*)(ws + WS_DCL);
    unsigned long long* agg = (unsigned long long*)(ws + WS_AGG);

    __shared__ float gl[2][128*68];  // 69,632 B double buffer
    __shared__ float shh[256];
    __shared__ float ohmf[64];

    int t = threadIdx.x, bid = blockIdx.x;
    int p = t >> 5, sub = t & 31;
    int r = p >> 2, h = p & 3;
    int irow = bid*4 + r;

    // staging: thread stages f32x4 chunks v = t + q*512 (q in [0,4))
    // LDS word = (v>>4)*68 + (v&15)*4 = (t>>4 + q*32)*68 + (t&15)*4
    const f32x4* gv4 = (const f32x4*)g;      // tile stride = 2048 f32x4
    float* w0 = &gl[0][(t >> 4)*68 + (t & 15)*4];
    float* w1 = &gl[1][(t >> 4)*68 + (t & 15)*4];

    float wv[16], gA[16];
    #pragma unroll
    for (int f = 0; f < 16; ++f)
        wv[f] = __uint_as_float(__builtin_amdgcn_readfirstlane(__float_as_uint(Wattn[f])));
    #pragma unroll
    for (int f = 0; f < 16; ++f) gA[f] = g[irow*64 + h*16 + f];

    float acc[16];
    #pragma unroll
    for (int f = 0; f < 16; ++f) acc[f] = 0.f;
    float lsum = 0.f;

    const float* dpt = dclT + h*2048 + sub;   // dj(tile,k) = dpt[tile*128+k*32]

    // ---- prologue: tiles 0,1 to regs; write tile0; dj for tiles 0,1 ----
    f32x4 s0[4], st[4];
    float djc[4], djn[4], djn2[4] = {0.f,0.f,0.f,0.f};
    #pragma unroll
    for (int q = 0; q < 4; ++q) { s0[q] = gv4[t + q*512]; st[q] = gv4[2048 + t + q*512]; }
    #pragma unroll
    for (int k = 0; k < 4; ++k) { djc[k] = dpt[k*32]; djn[k] = dpt[128 + k*32]; }
    #pragma unroll
    for (int q = 0; q < 4; ++q) *(f32x4*)(w0 + q*2176) = s0[q];   // 32*68 = 2176
    asm volatile("s_waitcnt lgkmcnt(0)\n\ts_barrier" ::: "memory");

    #pragma unroll
    for (int tile = 0; tile < 16; ++tile) {
        // write tile+1 into other buffer; issue loads for tile+2
        if (tile < 15) {
            float* wd = (tile & 1) ? w0 : w1;
            #pragma unroll
            for (int q = 0; q < 4; ++q) *(f32x4*)(wd + q*2176) = st[q];
        }
        if (tile < 14) {
            #pragma unroll
            for (int q = 0; q < 4; ++q) st[q] = gv4[(tile+2)*2048 + t + q*512];
            #pragma unroll
            for (int k = 0; k < 4; ++k) djn2[k] = dpt[(tile+2)*128 + k*32];
        }

        const float* bp = (tile & 1) ? &gl[1][0] : &gl[0][0];
        #pragma unroll
        for (int k = 0; k < 4; ++k) {
            const float* gj = bp + (k*32 + sub)*68 + h*16;
            f32x4 q0 = *(const f32x4*)(gj);
            f32x4 q1 = *(const f32x4*)(gj+4);
            f32x4 q2 = *(const f32x4*)(gj+8);
            f32x4 q3 = *(const f32x4*)(gj+12);
            float gvv[16] = { q0[0],q0[1],q0[2],q0[3], q1[0],q1[1],q1[2],q1[3],
                              q2[0],q2[1],q2[2],q2[3], q3[0],q3[1],q3[2],q3[3] };
            float s0a = 0.f, s1a = 0.f;
            #pragma unroll
            for (int f = 0; f < 16; f += 2) {
                float t0 = gA[f]   + gvv[f];
                float t1 = gA[f+1] + gvv[f+1];
                s0a = fmaf(wv[f],   fabsf(t0), s0a);   // |.| = free VOP3 modifier
                s1a = fmaf(wv[f+1], fabsf(t1), s1a);
            }
            float pj = __builtin_amdgcn_exp2f(fmaf(C1F, s0a + s1a, djc[k]));
            lsum += pj;
            #pragma unroll
            for (int f = 0; f < 16; ++f) acc[f] = fmaf(pj, gvv[f], acc[f]);
        }
        // lgkm-only barrier: ds ops visible; vmcnt prefetch stays in flight
        asm volatile("s_waitcnt lgkmcnt(0)\n\ts_barrier" ::: "memory");
        #pragma unroll
        for (int k = 0; k < 4; ++k) { djc[k] = djn[k]; djn[k] = djn2[k]; }
    }

    // 32-lane DPP reduction -> lanes 31 and 63
    float ls = dpp_sum32(lsum);
    float hv[16];
    #pragma unroll
    for (int f = 0; f < 16; ++f) hv[f] = dpp_sum32(acc[f]);

    if ((t & 31) == 31) {   // one leader lane per (row, head)
        float rl = 1.0f / ls;
        #pragma unroll
        for (int f = 0; f < 16; ++f) {
            float a = hv[f]*rl; a = fmaxf(a, 0.2f*a);
            hout[irow*64 + h*16 + f] = a;
            shh[r*64 + h*16 + f] = a;
        }
    }
    if (t < 64) {   // filled ohm for the block's 4 rows
        int rr = t >> 4, ll = t & 15;
        float v = ohm[(bid*4 + rr)*16 + ll];
        float s = v;
        #pragma unroll
        for (int m2 = 1; m2 < 16; m2 <<= 1) s += __shfl_xor(s, m2);
        ohmf[rr*16 + ll] = (s == 0.f) ? 0.0625f : v;
    }
    __syncthreads();

    // deterministic centroid partial agg: int64 fixed-point 2^26 (order-free)
    for (int v = t; v < 1024; v += 512) {
        int ll = v >> 6, d = v & 63;
        float s = 0.f;
        #pragma unroll
        for (int rr = 0; rr < 4; ++rr) s = fmaf(ohmf[rr*16 + ll], shh[rr*64 + d], s);
        atomicAdd(&agg[v], (unsigned long long)__float2ll_rn(s * 67108864.0f));
    }
}

// ---------------------------------------------------------------------------
// k_scores: rebuild centroids per block from agg/cnt, then cdist.
// ---------------------------------------------------------------------------
__global__ __launch_bounds__(256) void k_scores(
    unsigned char* __restrict__ ws, const float* __restrict__ hout,
    float* __restrict__ scores, float* __restrict__ missing)
{
    __shared__ float cl[16*68];
    unsigned long long* cnt = (unsigned long long*)(ws + WS_CNT);
    unsigned long long* agg = (unsigned long long*)(ws + WS_AGG);
    int t = threadIdx.x;

    for (int v = t; v < 1024; v += 256) {
        int ll = v >> 6, d = v & 63;
        long long a = (long long)agg[v];
        long long c = (long long)cnt[ll];
        cl[ll*68 + d] = (c == 0) ? 0.f : ((float)a / (float)c) * 0.015625f;
    }
    if (blockIdx.x == 0 && t < 16) missing[t] = (cnt[t] == 0) ? 1.0f : 0.0f;
    __syncthreads();

    int i = blockIdx.x*16 + (t >> 4), ll = t & 15;
    float s = 0.f;
    #pragma unroll 16
    for (int d = 0; d < 64; ++d) {
        float diff = hout[i*64 + d] - cl[ll*68 + d];
        s = fmaf(diff, diff, s);
    }
    scores[i*16 + ll] = -sqrtf(s);
}

// ---------------------------------------------------------------------------
extern "C" void kernel_launch(void* const* d_in, const int* in_sizes, int n_in,
                              void* d_out, int out_size, void* d_ws, size_t ws_size,
                              hipStream_t stream)
{
    const float* x     = (const float*)d_in[0];
    const float* ohm   = (const float*)d_in[1];
    const float* Wl    = (const float*)d_in[2];
    const float* Wattn = (const float*)d_in[3];
    unsigned char* ws  = (unsigned char*)d_ws;

    float* out     = (float*)d_out;
    float* scores  = out;
    float* hout    = out + 2048*16;
    float* missing = out + 2048*16 + 2048*64;

    hipMemsetAsync(d_ws, 0, 8320, stream);           // cnt + agg
    k_proj  <<<512, 256, 0, stream>>>(x, ohm, Wl, Wattn, ws);
    k_attn  <<<512, 512, 0, stream>>>(ohm, Wattn, ws, hout);
    k_scores<<<128, 256, 0, stream>>>(ws, hout, scores, missing);
}